// Round 4
// baseline (314.207 us; speedup 1.0000x reference)
//
#include <hip/hip_runtime.h>

#define NN 100000
#define NE 1600000
#define DD 128
#define BINW 32                    // nodes per bin
#define NBIN (NN / BINW)           // 3125 (exact: 3125*32 = 100000)
#define BCAP 1024                  // edges per bin: avg 512, sigma ~22.6 -> +22 sigma
#define NGRP (NE / 4)              // 400000 uint4 edge-groups
#define KAB ((NGRP + 255) / 256)   // 1563 blocks (= ceil(NN/64) for the gemm phase too)
#define LDSP 136                   // padded row: 128 + 8 shorts

typedef __bf16 bf16x8 __attribute__((ext_vector_type(8)));
typedef float  f32x4  __attribute__((ext_vector_type(4)));
typedef unsigned int u32x4 __attribute__((ext_vector_type(4)));

// ---------- bf16 helpers (RNE) ----------
__device__ __forceinline__ unsigned int f2bf(float f) {
    unsigned int u = __float_as_uint(f);
    return (u + 0x7FFFu + ((u >> 16) & 1u)) >> 16;
}
__device__ __forceinline__ float bflo(unsigned int u) { return __uint_as_float(u << 16); }
__device__ __forceinline__ float bfhi(unsigned int u) { return __uint_as_float(u & 0xFFFF0000u); }

// ---------- kernel 1: bin-scatter + gemm (y = bf16(x @ W)) ----------
// phase 1: 1 uint4 edge-group per thread; atomics on 3125 bin counters (low fanout,
//          LLC-pipelined), 8B stores into advancing bin regions (full-line friendly).
// phase 2: W fp32 -> LDS bf16 transposed (per block, kills the prep kernel),
//          then the proven 4-wave x 16-row MFMA tile with LDS-coalesced y store.
__global__ __launch_bounds__(256) void k_bin_gemm(const int* __restrict__ adj,
                                                  int* __restrict__ gcnt,
                                                  int2* __restrict__ binbuf,
                                                  const float* __restrict__ x,
                                                  const float* __restrict__ W,
                                                  unsigned short* __restrict__ y)
{
    __shared__ unsigned short wtb_s[DD * LDSP];    // 34816 B
    __shared__ unsigned short ytile[64 * LDSP];    // 17408 B (total 52224 <= 64K)

    const int b   = (int)blockIdx.x;
    const int tid = (int)threadIdx.x;

    // ---- phase 1: bin scatter ----
    {
        const int g = b * 256 + tid;
        if (g < NGRP) {
            const u32x4 s4 = __builtin_nontemporal_load((const u32x4*)adj + g);
            const u32x4 d4 = __builtin_nontemporal_load((const u32x4*)(adj + NE) + g);
            int pos[4];
            #pragma unroll
            for (int j = 0; j < 4; ++j)
                pos[j] = atomicAdd(&gcnt[(int)s4[j] >> 5], 1);   // 4 independent chains
            #pragma unroll
            for (int j = 0; j < 4; ++j)
                if (pos[j] < BCAP)
                    binbuf[((int)s4[j] >> 5) * BCAP + pos[j]] = make_int2((int)s4[j], (int)d4[j]);
        }
    }

    // ---- phase 2a: W fp32 [k][n] -> LDS bf16 [n][k] (transposed, padded rows) ----
    for (int i = tid; i < DD * DD; i += 256) {
        const int k = i >> 7, n = i & 127;
        wtb_s[n * LDSP + k] = (unsigned short)f2bf(W[i]);
    }
    __syncthreads();

    // ---- phase 2b: gemm tile b (64 rows) ----
    const int wave = tid >> 6;
    const int lane = tid & 63;
    const int quad = lane >> 4;
    const int l16  = lane & 15;
    const int mbase = b * 64 + wave * 16;
    const int m = mbase + l16;

    bf16x8 a[4];
    if (m < NN) {
        const float* arow = x + (size_t)m * DD + quad * 8;
        #pragma unroll
        for (int ks = 0; ks < 4; ++ks) {
            const f32x4 f0 = __builtin_nontemporal_load((const f32x4*)(arow + ks * 32));
            const f32x4 f1 = __builtin_nontemporal_load((const f32x4*)(arow + ks * 32 + 4));
            u32x4 p;
            p[0] = f2bf(f0[0]) | (f2bf(f0[1]) << 16);
            p[1] = f2bf(f0[2]) | (f2bf(f0[3]) << 16);
            p[2] = f2bf(f1[0]) | (f2bf(f1[1]) << 16);
            p[3] = f2bf(f1[2]) | (f2bf(f1[3]) << 16);
            a[ks] = __builtin_bit_cast(bf16x8, p);
        }
    } else {
        const u32x4 z = 0;
        #pragma unroll
        for (int ks = 0; ks < 4; ++ks) a[ks] = __builtin_bit_cast(bf16x8, z);
    }

    unsigned short* lrow = ytile + wave * 16 * LDSP;

    #pragma unroll
    for (int nt = 0; nt < 8; ++nt) {
        f32x4 c = {0.f, 0.f, 0.f, 0.f};
        const unsigned short* bcol = wtb_s + (nt * 16 + l16) * LDSP + quad * 8;
        #pragma unroll
        for (int ks = 0; ks < 4; ++ks) {
            const bf16x8 bb = __builtin_bit_cast(bf16x8, *(const uint4*)(bcol + ks * 32));
            c = __builtin_amdgcn_mfma_f32_16x16x32_bf16(a[ks], bb, c, 0, 0, 0);
        }
        // C/D: col = lane&15, row = quad*4 + reg (verified) -> stage in LDS
        #pragma unroll
        for (int r = 0; r < 4; ++r)
            lrow[(quad * 4 + r) * LDSP + nt * 16 + l16] = (unsigned short)f2bf(c[r]);
    }

    __syncthreads();

    // coalesced store-back: lane = row(l>>2) x 64B-chunk(l&3); 4x16B per lane
    const int r16   = lane >> 2;
    const int ch    = lane & 3;
    const int growr = b * 64 + wave * 16 + r16;
    if (growr < NN) {
        const unsigned short* lsrc = ytile + (wave * 16 + r16) * LDSP + ch * 32;
        unsigned short* gdst = y + (size_t)growr * DD + ch * 32;
        *(uint4*)(gdst + 0)  = *(const uint4*)(lsrc + 0);
        *(uint4*)(gdst + 8)  = *(const uint4*)(lsrc + 8);
        *(uint4*)(gdst + 16) = *(const uint4*)(lsrc + 16);
        *(uint4*)(gdst + 24) = *(const uint4*)(lsrc + 24);
    }
}

// ---------- kernel 2: in-LDS counting sort + aggregate ----------
// block = bin (32 nodes, ~512 edges). Sort edges into per-node LDS dst-lists
// (LDS atomics only — zero global atomics). Aggregate: 16-lane group owns one
// node (4 nodes/wave concurrent), 4 gather rows in flight, no shuffle reduces.
__global__ __launch_bounds__(256) void k_sortagg(const int2* __restrict__ binbuf,
                                                 const int* __restrict__ gcnt,
                                                 const unsigned short* __restrict__ y,
                                                 float* __restrict__ out)
{
    __shared__ int scnt[BINW];
    __shared__ int soff[BINW];
    __shared__ int scur[BINW];
    __shared__ int sdst[BCAP];     // 4 KB -> 8 blocks/CU

    const int b   = (int)blockIdx.x;
    const int tid = (int)threadIdx.x;
    const int lo  = b * BINW;
    int ne = gcnt[b];
    if (ne > BCAP) ne = BCAP;      // statistically never
    const int2* eb = binbuf + (size_t)b * BCAP;

    if (tid < BINW) scnt[tid] = 0;
    __syncthreads();

    // count (coalesced 8B reads; LDS atomics)
    for (int e = tid; e < ne; e += 256)
        atomicAdd(&scnt[eb[e].x - lo], 1);
    __syncthreads();

    // exclusive scan over 32 counters (naive — trivial at this width)
    if (tid < BINW) {
        int a = 0;
        for (int j = 0; j < tid; ++j) a += scnt[j];
        soff[tid] = a;
        scur[tid] = a;
    }
    __syncthreads();

    // place (re-read bin edges — L2 hit)
    for (int e = tid; e < ne; e += 256) {
        const int2 ed = eb[e];
        const int p = atomicAdd(&scur[ed.x - lo], 1);
        sdst[p] = ed.y;
    }
    __syncthreads();

    const int wave = tid >> 6;
    const int lane = tid & 63;
    const int eg   = lane >> 4;    // group id: owns one node
    const int h    = lane & 15;    // 16B column of the 256B bf16 row

    #define ACC(p) do {                                         \
        acc[0] += bflo((p).x); acc[1] += bfhi((p).x);           \
        acc[2] += bflo((p).y); acc[3] += bfhi((p).y);           \
        acc[4] += bflo((p).z); acc[5] += bfhi((p).z);           \
        acc[6] += bflo((p).w); acc[7] += bfhi((p).w);           \
    } while (0)

    #pragma unroll
    for (int jj = 0; jj < 2; ++jj) {                // 4 waves x 4 groups x 2 = 32 nodes
        const int j   = wave * 8 + jj * 4 + eg;
        const int deg = scnt[j];
        const int st  = soff[j];
        float acc[8] = {0.f,0.f,0.f,0.f,0.f,0.f,0.f,0.f};

        int i = 0;
        for (; i + 3 < deg; i += 4) {               // 4 rows in flight per group
            const int d0 = sdst[st + i];
            const int d1 = sdst[st + i + 1];
            const int d2 = sdst[st + i + 2];
            const int d3 = sdst[st + i + 3];
            const uint4 p0 = *(const uint4*)(y + (size_t)d0 * DD + h * 8);
            const uint4 p1 = *(const uint4*)(y + (size_t)d1 * DD + h * 8);
            const uint4 p2 = *(const uint4*)(y + (size_t)d2 * DD + h * 8);
            const uint4 p3 = *(const uint4*)(y + (size_t)d3 * DD + h * 8);
            ACC(p0); ACC(p1); ACC(p2); ACC(p3);
        }
        for (; i < deg; ++i) {
            const int d0 = sdst[st + i];
            const uint4 p0 = *(const uint4*)(y + (size_t)d0 * DD + h * 8);
            ACC(p0);
        }

        const float inv = 1.0f / fmaxf((float)deg, 1.0f);
        float* o = out + (size_t)(lo + j) * DD + h * 8;
        float4 w0 = {acc[0]*inv, acc[1]*inv, acc[2]*inv, acc[3]*inv};
        float4 w1 = {acc[4]*inv, acc[5]*inv, acc[6]*inv, acc[7]*inv};
        *(float4*)(o + 0) = w0;
        *(float4*)(o + 4) = w1;
    }
    #undef ACC
}

extern "C" void kernel_launch(void* const* d_in, const int* in_sizes, int n_in,
                              void* d_out, int out_size, void* d_ws, size_t ws_size,
                              hipStream_t stream) {
    const float* x   = (const float*)d_in[0];   // [N, 128] fp32
    const int*   adj = (const int*)d_in[1];     // [2, E] int32
    const float* W   = (const float*)d_in[2];   // [128, 128] fp32
    float* out = (float*)d_out;                 // [N, 128] fp32

    // ws: y (25.6 MB) | binbuf (25.6 MB) | gcnt (12.5 KB)  -- total < previous 51.7 MB
    unsigned short* y = (unsigned short*)d_ws;
    int2* binbuf = (int2*)(y + (size_t)NN * DD);
    int*  gcnt   = (int*)(binbuf + (size_t)NBIN * BCAP);

    hipMemsetAsync(gcnt, 0, NBIN * sizeof(int), stream);
    k_bin_gemm<<<KAB, 256, 0, stream>>>(adj, gcnt, binbuf, x, W, y);
    k_sortagg<<<NBIN, 256, 0, stream>>>(binbuf, gcnt, y, out);
}

// Round 6
// 266.602 us; speedup vs baseline: 1.1786x; 1.1786x over previous
//
#include <hip/hip_runtime.h>

#define NN 100000
#define NE 1600000
#define DD 128
#define CAP 64            // slots per node row (256 B, line-aligned)
#define SLICE_N 12500     // NN / 8 slices
#define FILL_BLOCKS 2048  // 256 blocks per slice; blockIdx&7 = slice (XCD affinity)
#define BPS (FILL_BLOCKS / 8)                  // 256 blocks/slice
#define NGRP (NE / 4)                          // 400000 uint4 edge-groups
#define GEMM_BLOCKS ((NN + 63) / 64)           // 1563
#define LDSP 136                               // padded row: 128 + 8 shorts

typedef __bf16 bf16x8 __attribute__((ext_vector_type(8)));
typedef float  f32x4  __attribute__((ext_vector_type(4)));
typedef unsigned int u32x4 __attribute__((ext_vector_type(4)));

// ---------- bf16 helpers (RNE) ----------
__device__ __forceinline__ unsigned int f2bf(float f) {
    unsigned int u = __float_as_uint(f);
    return (u + 0x7FFFu + ((u >> 16) & 1u)) >> 16;
}
__device__ __forceinline__ float bflo(unsigned int u) { return __uint_as_float(u << 16); }
__device__ __forceinline__ float bfhi(unsigned int u) { return __uint_as_float(u & 0xFFFF0000u); }

// ---------- one-shot: W fp32 [k][n] -> wtb bf16 [n][k]  +  zero cnt ----------
__global__ __launch_bounds__(256) void k_prep(const float* __restrict__ W,
                                              unsigned short* __restrict__ wtb,
                                              int* __restrict__ cnt)
{
    const int idx = blockIdx.x * 256 + (int)threadIdx.x;   // grid = 64 blocks = DD*DD threads
    const int k = idx >> 7, n = idx & 127;
    wtb[n * DD + k] = (unsigned short)f2bf(W[idx]);
    int4* c4 = (int4*)cnt;
    for (int i = idx; i < NN / 4; i += DD * DD) c4[i] = make_int4(0, 0, 0, 0);
}

// ---------- fused: every block does {fill chunk} then {its gemm tile} ----------
// Fill at full 2048-block parallelism; edge_dst stores NON-TEMPORAL to skip the
// L2 partial-line RMW thrash (WRITE_SIZE 63MB vs 6.4MB ideal in r3 counters).
__global__ __launch_bounds__(256, 8) void k_fused(const int* __restrict__ adj,
                                                  int* __restrict__ cnt,
                                                  int* __restrict__ edge_dst,
                                                  const float* __restrict__ x,
                                                  const unsigned short* __restrict__ wtb,
                                                  unsigned short* __restrict__ y)
{
    __shared__ unsigned short ytile[64 * LDSP];   // 17408 B -> 8 blocks/CU

    const int b   = (int)blockIdx.x;
    const int tid = (int)threadIdx.x;

    // ---- phase 1: fill (XCD-sliced, uint4 edge scan, batched atomics) ----
    {
        const int slice = b & 7;
        const int w     = b >> 3;                 // 0..255
        const int lo    = slice * SLICE_N;
        const u32x4* src4 = (const u32x4*)adj;
        const u32x4* dst4 = (const u32x4*)(adj + NE);
        const int stride  = BPS * 256;            // 65536

        for (int g = w * 256 + tid; g < NGRP; g += stride) {
            const u32x4 s4 = __builtin_nontemporal_load(src4 + g);
            const u32x4 d4 = __builtin_nontemporal_load(dst4 + g);
            int sv[4], dv[4], slot[4];
            #pragma unroll
            for (int j = 0; j < 4; ++j) { sv[j] = (int)s4[j]; dv[j] = (int)d4[j]; }
            #pragma unroll
            for (int j = 0; j < 4; ++j) {
                slot[j] = ((unsigned)(sv[j] - lo) < (unsigned)SLICE_N)
                          ? atomicAdd(&cnt[sv[j]], 1) : CAP;
            }
            #pragma unroll
            for (int j = 0; j < 4; ++j) {
                if (slot[j] < CAP)
                    __builtin_nontemporal_store(dv[j],
                        edge_dst + (size_t)sv[j] * CAP + slot[j]);
            }
        }
    }

    // ---- phase 2: gemm tile b (64 rows), y = bf16(x @ Wt) ----
    if (b >= GEMM_BLOCKS) return;

    const int wave = tid >> 6;
    const int lane = tid & 63;
    const int quad = lane >> 4;
    const int l16  = lane & 15;
    const int mbase = b * 64 + wave * 16;
    const int m = mbase + l16;

    bf16x8 a[4];
    if (m < NN) {
        const float* arow = x + (size_t)m * DD + quad * 8;
        #pragma unroll
        for (int ks = 0; ks < 4; ++ks) {
            const f32x4 f0 = __builtin_nontemporal_load((const f32x4*)(arow + ks * 32));
            const f32x4 f1 = __builtin_nontemporal_load((const f32x4*)(arow + ks * 32 + 4));
            u32x4 p;
            p[0] = f2bf(f0[0]) | (f2bf(f0[1]) << 16);
            p[1] = f2bf(f0[2]) | (f2bf(f0[3]) << 16);
            p[2] = f2bf(f1[0]) | (f2bf(f1[1]) << 16);
            p[3] = f2bf(f1[2]) | (f2bf(f1[3]) << 16);
            a[ks] = __builtin_bit_cast(bf16x8, p);
        }
    } else {
        const u32x4 z = 0;
        #pragma unroll
        for (int ks = 0; ks < 4; ++ks) a[ks] = __builtin_bit_cast(bf16x8, z);
    }

    unsigned short* lrow = ytile + wave * 16 * LDSP;

    #pragma unroll
    for (int nt = 0; nt < 8; ++nt) {
        f32x4 c = {0.f, 0.f, 0.f, 0.f};
        const unsigned short* bcol = wtb + (nt * 16 + l16) * DD + quad * 8;
        #pragma unroll
        for (int ks = 0; ks < 4; ++ks) {
            const bf16x8 bb = __builtin_bit_cast(bf16x8, *(const uint4*)(bcol + ks * 32));
            c = __builtin_amdgcn_mfma_f32_16x16x32_bf16(a[ks], bb, c, 0, 0, 0);
        }
        // C/D: col = lane&15, row = quad*4 + reg (verified) -> stage in LDS
        #pragma unroll
        for (int r = 0; r < 4; ++r)
            lrow[(quad * 4 + r) * LDSP + nt * 16 + l16] = (unsigned short)f2bf(c[r]);
    }

    __syncthreads();

    // coalesced store-back: lane = row(l>>2) x 64B-chunk(l&3); 4x16B per lane
    const int r16   = lane >> 2;
    const int ch    = lane & 3;
    const int growr = b * 64 + wave * 16 + r16;
    if (growr < NN) {
        const unsigned short* lsrc = ytile + (wave * 16 + r16) * LDSP + ch * 32;
        unsigned short* gdst = y + (size_t)growr * DD + ch * 32;
        *(uint4*)(gdst + 0)  = *(const uint4*)(lsrc + 0);
        *(uint4*)(gdst + 8)  = *(const uint4*)(lsrc + 8);
        *(uint4*)(gdst + 16) = *(const uint4*)(lsrc + 16);
        *(uint4*)(gdst + 24) = *(const uint4*)(lsrc + 24);
    }
}

// ---------- aggregate v3: 16-lane group OWNS one node (4 nodes/wave, no shuffles) ----------
// 8-deep gather unroll (avg deg=16 -> typically one 8-deep batch + remainder),
// doubling outstanding loads per lane vs the old wave-per-node stride-4 layout.
__global__ __launch_bounds__(256) void k_agg3(const unsigned short* __restrict__ y,
                                              const int* __restrict__ cnt,
                                              const int* __restrict__ edge_dst,
                                              float* __restrict__ out)
{
    const int tid  = (int)threadIdx.x;
    const int wave = tid >> 6;
    const int lane = tid & 63;
    const int eg   = lane >> 4;                   // group: owns one node
    const int h    = lane & 15;                   // 16B column of the 256B bf16 row
    const int n    = (int)blockIdx.x * 16 + wave * 4 + eg;

    int deg = cnt[n];
    if (deg > CAP) deg = CAP;                     // never in practice
    const int* el = edge_dst + (size_t)n * CAP;

    float acc[8] = {0.f,0.f,0.f,0.f,0.f,0.f,0.f,0.f};

    #define ACC(p) do {                                         \
        acc[0] += bflo((p).x); acc[1] += bfhi((p).x);           \
        acc[2] += bflo((p).y); acc[3] += bfhi((p).y);           \
        acc[4] += bflo((p).z); acc[5] += bfhi((p).z);           \
        acc[6] += bflo((p).w); acc[7] += bfhi((p).w);           \
    } while (0)

    int i = 0;
    for (; i + 7 < deg; i += 8) {                 // 8 gather rows in flight per lane
        const int d0 = el[i];
        const int d1 = el[i + 1];
        const int d2 = el[i + 2];
        const int d3 = el[i + 3];
        const int d4 = el[i + 4];
        const int d5 = el[i + 5];
        const int d6 = el[i + 6];
        const int d7 = el[i + 7];
        const uint4 p0 = *(const uint4*)(y + (size_t)d0 * DD + h * 8);
        const uint4 p1 = *(const uint4*)(y + (size_t)d1 * DD + h * 8);
        const uint4 p2 = *(const uint4*)(y + (size_t)d2 * DD + h * 8);
        const uint4 p3 = *(const uint4*)(y + (size_t)d3 * DD + h * 8);
        const uint4 p4 = *(const uint4*)(y + (size_t)d4 * DD + h * 8);
        const uint4 p5 = *(const uint4*)(y + (size_t)d5 * DD + h * 8);
        const uint4 p6 = *(const uint4*)(y + (size_t)d6 * DD + h * 8);
        const uint4 p7 = *(const uint4*)(y + (size_t)d7 * DD + h * 8);
        ACC(p0); ACC(p1); ACC(p2); ACC(p3);
        ACC(p4); ACC(p5); ACC(p6); ACC(p7);
    }
    for (; i + 3 < deg; i += 4) {
        const int d0 = el[i];
        const int d1 = el[i + 1];
        const int d2 = el[i + 2];
        const int d3 = el[i + 3];
        const uint4 p0 = *(const uint4*)(y + (size_t)d0 * DD + h * 8);
        const uint4 p1 = *(const uint4*)(y + (size_t)d1 * DD + h * 8);
        const uint4 p2 = *(const uint4*)(y + (size_t)d2 * DD + h * 8);
        const uint4 p3 = *(const uint4*)(y + (size_t)d3 * DD + h * 8);
        ACC(p0); ACC(p1); ACC(p2); ACC(p3);
    }
    for (; i < deg; ++i) {
        const int d0 = el[i];
        const uint4 p0 = *(const uint4*)(y + (size_t)d0 * DD + h * 8);
        ACC(p0);
    }
    #undef ACC

    // group owns the node: no cross-lane reduction needed
    const float inv = 1.0f / fmaxf((float)deg, 1.0f);
    float* o = out + (size_t)n * DD + h * 8;
    float4 w0 = {acc[0]*inv, acc[1]*inv, acc[2]*inv, acc[3]*inv};
    float4 w1 = {acc[4]*inv, acc[5]*inv, acc[6]*inv, acc[7]*inv};
    *(float4*)(o + 0) = w0;
    *(float4*)(o + 4) = w1;
}

extern "C" void kernel_launch(void* const* d_in, const int* in_sizes, int n_in,
                              void* d_out, int out_size, void* d_ws, size_t ws_size,
                              hipStream_t stream) {
    const float* x   = (const float*)d_in[0];   // [N, 128] fp32
    const int*   adj = (const int*)d_in[1];     // [2, E] int32
    const float* W   = (const float*)d_in[2];   // [128, 128] fp32
    float* out = (float*)d_out;                 // [N, 128] fp32

    // ws: y (25.6 MB) | wtb (32 KB) | cnt (0.4 MB) | edge_dst (25.6 MB)
    unsigned short* y   = (unsigned short*)d_ws;
    unsigned short* wtb = y + (size_t)NN * DD;
    int* cnt      = (int*)(wtb + DD * DD);
    int* edge_dst = cnt + NN;

    k_prep <<<DD * DD / 256, 256, 0, stream>>>(W, wtb, cnt);
    k_fused<<<FILL_BLOCKS, 256, 0, stream>>>(adj, cnt, edge_dst, x, wtb, y);
    k_agg3 <<<NN / 16, 256, 0, stream>>>(y, cnt, edge_dst, out);
}

// Round 7
// 254.317 us; speedup vs baseline: 1.2355x; 1.0483x over previous
//
#include <hip/hip_runtime.h>

#define NN 100000
#define NE 1600000
#define DD 128
#define CAP 64            // slots per node row (256 B, line-aligned)
#define SLICE_N 12500     // NN / 8 slices
#define FILL_BLOCKS 2048  // 256 blocks per slice; blockIdx&7 = slice (XCD affinity)
#define BPS (FILL_BLOCKS / 8)                  // 256 blocks/slice
#define NGRP (NE / 4)                          // 400000 uint4 edge-groups
#define GEMM_BLOCKS ((NN + 63) / 64)           // 1563
#define LDSP 136                               // padded row: 128 + 8 shorts

typedef __bf16 bf16x8 __attribute__((ext_vector_type(8)));
typedef float  f32x4  __attribute__((ext_vector_type(4)));
typedef unsigned int u32x4 __attribute__((ext_vector_type(4)));

// ---------- bf16 helpers (RNE) ----------
__device__ __forceinline__ unsigned int f2bf(float f) {
    unsigned int u = __float_as_uint(f);
    return (u + 0x7FFFu + ((u >> 16) & 1u)) >> 16;
}
__device__ __forceinline__ float bflo(unsigned int u) { return __uint_as_float(u << 16); }
__device__ __forceinline__ float bfhi(unsigned int u) { return __uint_as_float(u & 0xFFFF0000u); }

// ---------- one-shot: W fp32 [k][n] -> wtb bf16 [n][k]  +  zero cnt ----------
__global__ __launch_bounds__(256) void k_prep(const float* __restrict__ W,
                                              unsigned short* __restrict__ wtb,
                                              int* __restrict__ cnt)
{
    const int idx = blockIdx.x * 256 + (int)threadIdx.x;   // grid = 64 blocks = DD*DD threads
    const int k = idx >> 7, n = idx & 127;
    wtb[n * DD + k] = (unsigned short)f2bf(W[idx]);
    int4* c4 = (int4*)cnt;
    for (int i = idx; i < NN / 4; i += DD * DD) c4[i] = make_int4(0, 0, 0, 0);
}

// ---------- fused: every block does {fill chunk} then {its gemm tile} ----------
// r6 lessons applied: edge_dst stores go through L2 (plain stores — NT regressed,
// WRITE 106->124 MB). NEW this round: gemm A-frag x-loads are ISSUED BEFORE the
// fill loop so their HBM latency hides under fill's atomic-stalled 84 us.
__global__ __launch_bounds__(256, 8) void k_fused(const int* __restrict__ adj,
                                                  int* __restrict__ cnt,
                                                  int* __restrict__ edge_dst,
                                                  const float* __restrict__ x,
                                                  const unsigned short* __restrict__ wtb,
                                                  unsigned short* __restrict__ y)
{
    __shared__ unsigned short ytile[64 * LDSP];   // 17408 B -> 8 blocks/CU

    const int b   = (int)blockIdx.x;
    const int tid = (int)threadIdx.x;
    const int wave = tid >> 6;
    const int lane = tid & 63;
    const int quad = lane >> 4;
    const int l16  = lane & 15;
    const int mbase = b * 64 + wave * 16;
    const int m = mbase + l16;

    // ---- issue gemm A-loads EARLY: latency hides under the fill phase ----
    f32x4 af[8];
    const bool amask = (b < GEMM_BLOCKS) && (m < NN);
    if (amask) {
        const float* arow = x + (size_t)m * DD + quad * 8;
        #pragma unroll
        for (int ks = 0; ks < 4; ++ks) {
            af[2 * ks + 0] = __builtin_nontemporal_load((const f32x4*)(arow + ks * 32));
            af[2 * ks + 1] = __builtin_nontemporal_load((const f32x4*)(arow + ks * 32 + 4));
        }
    }

    // ---- phase 1: fill (XCD-sliced, uint4 edge scan, batched atomics) ----
    {
        const int slice = b & 7;
        const int w     = b >> 3;                 // 0..255
        const int lo    = slice * SLICE_N;
        const u32x4* src4 = (const u32x4*)adj;
        const u32x4* dst4 = (const u32x4*)(adj + NE);
        const int stride  = BPS * 256;            // 65536

        for (int g = w * 256 + tid; g < NGRP; g += stride) {
            const u32x4 s4 = __builtin_nontemporal_load(src4 + g);
            const u32x4 d4 = __builtin_nontemporal_load(dst4 + g);
            int sv[4], dv[4], slot[4];
            #pragma unroll
            for (int j = 0; j < 4; ++j) { sv[j] = (int)s4[j]; dv[j] = (int)d4[j]; }
            #pragma unroll
            for (int j = 0; j < 4; ++j) {
                slot[j] = ((unsigned)(sv[j] - lo) < (unsigned)SLICE_N)
                          ? atomicAdd(&cnt[sv[j]], 1) : CAP;
            }
            #pragma unroll
            for (int j = 0; j < 4; ++j) {
                if (slot[j] < CAP)
                    edge_dst[(size_t)sv[j] * CAP + slot[j]] = dv[j];   // L2-merged store
            }
        }
    }

    // ---- phase 2: gemm tile b (64 rows), y = bf16(x @ Wt) ----
    if (b >= GEMM_BLOCKS) return;

    bf16x8 a[4];
    if (amask) {
        #pragma unroll
        for (int ks = 0; ks < 4; ++ks) {
            const f32x4 f0 = af[2 * ks + 0];
            const f32x4 f1 = af[2 * ks + 1];
            u32x4 p;
            p[0] = f2bf(f0[0]) | (f2bf(f0[1]) << 16);
            p[1] = f2bf(f0[2]) | (f2bf(f0[3]) << 16);
            p[2] = f2bf(f1[0]) | (f2bf(f1[1]) << 16);
            p[3] = f2bf(f1[2]) | (f2bf(f1[3]) << 16);
            a[ks] = __builtin_bit_cast(bf16x8, p);
        }
    } else {
        const u32x4 z = 0;
        #pragma unroll
        for (int ks = 0; ks < 4; ++ks) a[ks] = __builtin_bit_cast(bf16x8, z);
    }

    unsigned short* lrow = ytile + wave * 16 * LDSP;

    #pragma unroll
    for (int nt = 0; nt < 8; ++nt) {
        f32x4 c = {0.f, 0.f, 0.f, 0.f};
        const unsigned short* bcol = wtb + (nt * 16 + l16) * DD + quad * 8;
        #pragma unroll
        for (int ks = 0; ks < 4; ++ks) {
            const bf16x8 bb = __builtin_bit_cast(bf16x8, *(const uint4*)(bcol + ks * 32));
            c = __builtin_amdgcn_mfma_f32_16x16x32_bf16(a[ks], bb, c, 0, 0, 0);
        }
        // C/D: col = lane&15, row = quad*4 + reg (verified) -> stage in LDS
        #pragma unroll
        for (int r = 0; r < 4; ++r)
            lrow[(quad * 4 + r) * LDSP + nt * 16 + l16] = (unsigned short)f2bf(c[r]);
    }

    __syncthreads();

    // coalesced store-back: lane = row(l>>2) x 64B-chunk(l&3); 4x16B per lane
    const int r16   = lane >> 2;
    const int ch    = lane & 3;
    const int growr = b * 64 + wave * 16 + r16;
    if (growr < NN) {
        const unsigned short* lsrc = ytile + (wave * 16 + r16) * LDSP + ch * 32;
        unsigned short* gdst = y + (size_t)growr * DD + ch * 32;
        *(uint4*)(gdst + 0)  = *(const uint4*)(lsrc + 0);
        *(uint4*)(gdst + 8)  = *(const uint4*)(lsrc + 8);
        *(uint4*)(gdst + 16) = *(const uint4*)(lsrc + 16);
        *(uint4*)(gdst + 24) = *(const uint4*)(lsrc + 24);
    }
}

// ---------- aggregate: 1 wave/node, 4 edge-groups x 16 lanes x 16B bf16 loads ----------
// (r2's proven agg2 — r6's group-per-node variant regressed ~7 us from degree divergence)
__global__ __launch_bounds__(256) void k_agg2(const unsigned short* __restrict__ y,
                                              const int* __restrict__ cnt,
                                              const int* __restrict__ edge_dst,
                                              float* __restrict__ out)
{
    const int n    = blockIdx.x * 4 + ((int)threadIdx.x >> 6);
    const int lane = (int)threadIdx.x & 63;
    const int eg   = lane >> 4;
    const int h    = lane & 15;
    int deg = cnt[n];
    if (deg > CAP) deg = CAP;                   // never in practice
    const int* el = edge_dst + (size_t)n * CAP;

    float acc[8] = {0.f,0.f,0.f,0.f,0.f,0.f,0.f,0.f};

    #define ACC(p) do {                                         \
        acc[0] += bflo((p).x); acc[1] += bfhi((p).x);           \
        acc[2] += bflo((p).y); acc[3] += bfhi((p).y);           \
        acc[4] += bflo((p).z); acc[5] += bfhi((p).z);           \
        acc[6] += bflo((p).w); acc[7] += bfhi((p).w);           \
    } while (0)

    int i = eg;
    for (; i + 12 < deg; i += 16) {
        const int d0 = el[i];
        const int d1 = el[i + 4];
        const int d2 = el[i + 8];
        const int d3 = el[i + 12];
        const uint4 p0 = *(const uint4*)(y + (size_t)d0 * DD + h * 8);
        const uint4 p1 = *(const uint4*)(y + (size_t)d1 * DD + h * 8);
        const uint4 p2 = *(const uint4*)(y + (size_t)d2 * DD + h * 8);
        const uint4 p3 = *(const uint4*)(y + (size_t)d3 * DD + h * 8);
        ACC(p0); ACC(p1); ACC(p2); ACC(p3);
    }
    for (; i + 4 < deg; i += 8) {
        const int d0 = el[i];
        const int d1 = el[i + 4];
        const uint4 p0 = *(const uint4*)(y + (size_t)d0 * DD + h * 8);
        const uint4 p1 = *(const uint4*)(y + (size_t)d1 * DD + h * 8);
        ACC(p0); ACC(p1);
    }
    for (; i < deg; i += 4) {
        const int d0 = el[i];
        const uint4 p0 = *(const uint4*)(y + (size_t)d0 * DD + h * 8);
        ACC(p0);
    }
    #undef ACC

    #pragma unroll
    for (int j = 0; j < 8; ++j) {
        acc[j] += __shfl_xor(acc[j], 16, 64);
        acc[j] += __shfl_xor(acc[j], 32, 64);
    }

    if (eg == 0) {
        const float inv = 1.0f / fmaxf((float)deg, 1.0f);
        float* o = out + (size_t)n * DD + h * 8;
        float4 w0 = {acc[0]*inv, acc[1]*inv, acc[2]*inv, acc[3]*inv};
        float4 w1 = {acc[4]*inv, acc[5]*inv, acc[6]*inv, acc[7]*inv};
        *(float4*)(o + 0) = w0;
        *(float4*)(o + 4) = w1;
    }
}

extern "C" void kernel_launch(void* const* d_in, const int* in_sizes, int n_in,
                              void* d_out, int out_size, void* d_ws, size_t ws_size,
                              hipStream_t stream) {
    const float* x   = (const float*)d_in[0];   // [N, 128] fp32
    const int*   adj = (const int*)d_in[1];     // [2, E] int32
    const float* W   = (const float*)d_in[2];   // [128, 128] fp32
    float* out = (float*)d_out;                 // [N, 128] fp32

    // ws: y (25.6 MB) | wtb (32 KB) | cnt (0.4 MB) | edge_dst (25.6 MB)
    unsigned short* y   = (unsigned short*)d_ws;
    unsigned short* wtb = y + (size_t)NN * DD;
    int* cnt      = (int*)(wtb + DD * DD);
    int* edge_dst = cnt + NN;

    k_prep <<<DD * DD / 256, 256, 0, stream>>>(W, wtb, cnt);
    k_fused<<<FILL_BLOCKS, 256, 0, stream>>>(adj, cnt, edge_dst, x, wtb, y);
    k_agg2 <<<NN / 4, 256, 0, stream>>>(y, cnt, edge_dst, out);
}